// Round 1
// 316.625 us; speedup vs baseline: 1.0527x; 1.0527x over previous
//
#include <hip/hip_runtime.h>
#include <stdint.h>

// ---------------------------------------------------------------------------
// SelfAttention: out[b,n,d] = ( softmax( (X^T Wk)(X^T Wq)^T / 32 ) (X^T Wv) )^T
// B=16, N=D=1024.  Five 1024^3 matmuls as gemm_bt (C[m,n] = sum_k A[m,k]*B[n,k]).
//
// R2: XCD swizzle -> FETCH 154->33 MB.  R3: BK=64 + LDS-staged bf16 epilogue.
// R4 (this): 256x256 8-phase schedule (T3+T4+T5 from the technique catalog).
//   - 512 thr / 8 waves (2M x 4N), per-wave 128x64 out, BK=64, 16 K-tiles.
//   - LDS 128 KiB: 2 buffers x (A 256x64 + B 256x64) bf16.  Same XOR-chunk
//     swizzle as R3 (slot cp holds k-chunk cp^(row&7)): ds_read_b128
//     conflict-free (R3 counter-verified 0).
//   - 4 phases per K-tile; per phase: {ds_read frag set | stage one 16KiB set
//     of tile t+1 (2x global_load_lds)} -> counted vmcnt -> s_barrier ->
//     lgkmcnt(0)+sched_barrier -> setprio(1) 16xMFMA setprio(0) -> s_barrier.
//   - Staging order per tile t (into buf nxt): P1:A-a  P2:B-a  P3:B-b  P4:A-b.
//     Phase LDS-read sets:  P1:{A-a,B-a}  P2:{B-b}  P3:{A-b}  P4:{} (regs).
//     vmcnt invariants (per wave, 2 loads per stage set):
//       P1 wait vmcnt(4): outstanding [Bb(t),Ab(t),Aa(t+1)]=6 -> Bb(t) done
//       P2 wait vmcnt(4): outstanding [Ab(t),Aa(t+1),Ba(t+1)]=6 -> Ab(t) done
//       P3 no wait (P4 reads registers only)
//       P4 wait vmcnt(4): outstanding [Aa,Ba,Bb,Ab](t+1)=8 -> Aa,Ba(t+1) done
//     Never vmcnt(0) in the main loop.  NOTE: correctness of the counted
//     waits assumes no scratch (spill) VMEM ops in the loop; VGPR budget
//     ~220 < 256 @ __launch_bounds__(512,2).
// ---------------------------------------------------------------------------

typedef __bf16 bf16x8_t __attribute__((ext_vector_type(8)));
typedef float  f32x4_t  __attribute__((ext_vector_type(4)));

typedef __attribute__((address_space(3))) uint32_t as3_u32;
typedef __attribute__((address_space(1))) uint32_t as1_u32;

__device__ __forceinline__ void async_copy16(const void* g, const void* l) {
  __builtin_amdgcn_global_load_lds((const as1_u32*)(uintptr_t)g,
                                   (as3_u32*)(uint32_t)(uintptr_t)l,
                                   16, 0, 0);
}

__device__ __forceinline__ uint16_t f2bf(float f) {  // RNE
  uint32_t x = __float_as_uint(f);
  return (uint16_t)((x + 0x7fffu + ((x >> 16) & 1u)) >> 16);
}
__device__ __forceinline__ float bf2f(uint16_t b) {
  return __uint_as_float(((uint32_t)b) << 16);
}

// C[m,n] = alpha * sum_k A[m,k] * B[n,k].  M=N=K=1024 fixed.  256 blocks x 512.
template <bool OUT_F32>
__global__ __launch_bounds__(512, 2)
void gemm_bt256(const uint16_t* __restrict__ A, const uint16_t* __restrict__ B,
                void* __restrict__ Cv, size_t sA, size_t sB, size_t sC,
                float alpha)
{
  __shared__ __align__(16) char smem[131072];

  // ---- XCD-aware swizzle: lid%8 = XCD; 2 batches per XCD, 4x4 tiles/batch --
  const int lid  = blockIdx.x;
  const int xcd  = lid & 7;
  const int slot = lid >> 3;            // 0..31
  const int z    = (xcd << 1) | (slot >> 4);
  const int t16  = slot & 15;
  const int bm0  = (t16 >> 2) << 8;
  const int bn0  = (t16 & 3) << 8;

  A += (size_t)z * sA + ((size_t)bm0 << 10);
  B += (size_t)z * sB + ((size_t)bn0 << 10);

  const int t    = threadIdx.x;
  const int lane = t & 63;
  const int w    = t >> 6;
  const int q    = lane >> 4;
  const int r16  = lane & 15;
  const int wm   = (w >> 2) << 7;       // 0,128
  const int wn   = (w & 3) << 6;        // 0,64,128,192

  // ---- staging per-thread constants (XOR-chunk swizzled source) ----
  const int g0  = t >> 3;               // 0..63
  const int cp  = t & 7;                // LDS chunk slot
  const int ce  = (cp ^ (g0 & 7)) << 3; // logical k-chunk elem offset
  const int sAo = (g0 << 7) + (cp << 4);
  const int rB  = ((g0 >> 5) << 6) + (g0 & 31);
  const int sBo = (rB << 7) + (cp << 4);
  const uint16_t* Ab = A + ((size_t)g0 << 10) + ce;
  const uint16_t* Bb = B + ((size_t)rB << 10) + ce;

  // A set s (a=0 rows {0-63,128-191}, b=1 rows {64-127,192-255}): 2 loads.
#define STAGE_A(s, kge, dst) do {                                              \
    async_copy16(Ab + (((s)*64 +   0) << 10) + (kge),                          \
                 smem + (dst) + sAo + (s)*8192);                               \
    async_copy16(Ab + (((s)*64 + 128) << 10) + (kge),                          \
                 smem + (dst) + sAo + (s)*8192 + 16384);                       \
  } while (0)
  // B set s (a=0 rows {0-31,64-95,128-159,192-223}, b=1 those +32): 2 loads.
#define STAGE_B(s, kge, dst) do {                                              \
    async_copy16(Bb + (((s)*32 +   0) << 10) + (kge),                          \
                 smem + (dst) + 32768 + sBo + (s)*4096);                       \
    async_copy16(Bb + (((s)*32 + 128) << 10) + (kge),                          \
                 smem + (dst) + 32768 + sBo + (s)*4096 + 16384);               \
  } while (0)

  // ---- fragment read bases (buffer 0); row&7 == r16&7 for all mi/wm ----
  const int sl0 = ((0 + q) ^ (r16 & 7)) << 4;
  const int sl1 = ((4 + q) ^ (r16 & 7)) << 4;
  int aRd0 = ((wm + r16) << 7) + sl0;
  int aRd1 = ((wm + r16) << 7) + sl1;
  int bRd0 = 32768 + ((wn + r16) << 7) + sl0;
  int bRd1 = 32768 + ((wn + r16) << 7) + sl1;

  f32x4_t acc[8][4];
#pragma unroll
  for (int i = 0; i < 8; i++)
#pragma unroll
    for (int j = 0; j < 4; j++) acc[i][j] = (f32x4_t){0.f, 0.f, 0.f, 0.f};

  // ---- prologue: stage tile 0 into buffer 0 (order Aa, Ba, Bb, Ab) ----
  STAGE_A(0, 0, 0);
  STAGE_B(0, 0, 0);
  STAGE_B(1, 0, 0);
  STAGE_A(1, 0, 0);
  asm volatile("s_waitcnt vmcnt(4)" ::: "memory");
  __builtin_amdgcn_s_barrier();

  int nxt = 65536;
  for (int t0 = 0; t0 < 16; ++t0) {
    const int kge = ((t0 + 1) & 15) << 6;   // t0=15 wraps to 0: garbage, unread
    bf16x8_t af[4][2], bfA[2][2], bfB[2][2];

    // ================= P1: quad (m0, nA); reads A-a, B-a =================
#pragma unroll
    for (int mi = 0; mi < 4; ++mi) {
      af[mi][0] = *(const bf16x8_t*)(smem + aRd0 + mi * 2048);
      af[mi][1] = *(const bf16x8_t*)(smem + aRd1 + mi * 2048);
    }
#pragma unroll
    for (int ni = 0; ni < 2; ++ni) {
      bfA[ni][0] = *(const bf16x8_t*)(smem + bRd0 + ni * 2048);
      bfA[ni][1] = *(const bf16x8_t*)(smem + bRd1 + ni * 2048);
    }
    STAGE_A(0, kge, nxt);
    asm volatile("s_waitcnt vmcnt(4)" ::: "memory");
    __builtin_amdgcn_s_barrier();
    asm volatile("s_waitcnt lgkmcnt(0)" ::: "memory");
    __builtin_amdgcn_sched_barrier(0);
    __builtin_amdgcn_s_setprio(1);
#pragma unroll
    for (int kk = 0; kk < 2; ++kk)
#pragma unroll
      for (int mi = 0; mi < 4; ++mi)
#pragma unroll
        for (int ni = 0; ni < 2; ++ni)
          acc[mi][ni] = __builtin_amdgcn_mfma_f32_16x16x32_bf16(
              af[mi][kk], bfA[ni][kk], acc[mi][ni], 0, 0, 0);
    __builtin_amdgcn_s_setprio(0);
    __builtin_amdgcn_s_barrier();

    // ================= P2: quad (m0, nB); reads B-b =================
#pragma unroll
    for (int ni = 0; ni < 2; ++ni) {
      bfB[ni][0] = *(const bf16x8_t*)(smem + bRd0 + 4096 + ni * 2048);
      bfB[ni][1] = *(const bf16x8_t*)(smem + bRd1 + 4096 + ni * 2048);
    }
    STAGE_B(0, kge, nxt);
    asm volatile("s_waitcnt vmcnt(4)" ::: "memory");
    __builtin_amdgcn_s_barrier();
    asm volatile("s_waitcnt lgkmcnt(0)" ::: "memory");
    __builtin_amdgcn_sched_barrier(0);
    __builtin_amdgcn_s_setprio(1);
#pragma unroll
    for (int kk = 0; kk < 2; ++kk)
#pragma unroll
      for (int mi = 0; mi < 4; ++mi)
#pragma unroll
        for (int ni = 0; ni < 2; ++ni)
          acc[mi][2 + ni] = __builtin_amdgcn_mfma_f32_16x16x32_bf16(
              af[mi][kk], bfB[ni][kk], acc[mi][2 + ni], 0, 0, 0);
    __builtin_amdgcn_s_setprio(0);
    __builtin_amdgcn_s_barrier();

    // ================= P3: quad (m1, nB); reads A-b =================
#pragma unroll
    for (int mi = 0; mi < 4; ++mi) {
      af[mi][0] = *(const bf16x8_t*)(smem + aRd0 + 8192 + mi * 2048);
      af[mi][1] = *(const bf16x8_t*)(smem + aRd1 + 8192 + mi * 2048);
    }
    STAGE_B(1, kge, nxt);
    // no vmcnt: P4 reads registers only
    __builtin_amdgcn_s_barrier();
    asm volatile("s_waitcnt lgkmcnt(0)" ::: "memory");
    __builtin_amdgcn_sched_barrier(0);
    __builtin_amdgcn_s_setprio(1);
#pragma unroll
    for (int kk = 0; kk < 2; ++kk)
#pragma unroll
      for (int mi = 0; mi < 4; ++mi)
#pragma unroll
        for (int ni = 0; ni < 2; ++ni)
          acc[4 + mi][2 + ni] = __builtin_amdgcn_mfma_f32_16x16x32_bf16(
              af[mi][kk], bfB[ni][kk], acc[4 + mi][2 + ni], 0, 0, 0);
    __builtin_amdgcn_s_setprio(0);
    __builtin_amdgcn_s_barrier();

    // ================= P4: quad (m1, nA); register-only =================
    STAGE_A(1, kge, nxt);
    asm volatile("s_waitcnt vmcnt(4)" ::: "memory");
    __builtin_amdgcn_s_barrier();
    __builtin_amdgcn_s_setprio(1);
#pragma unroll
    for (int kk = 0; kk < 2; ++kk)
#pragma unroll
      for (int mi = 0; mi < 4; ++mi)
#pragma unroll
        for (int ni = 0; ni < 2; ++ni)
          acc[4 + mi][ni] = __builtin_amdgcn_mfma_f32_16x16x32_bf16(
              af[mi][kk], bfA[ni][kk], acc[4 + mi][ni], 0, 0, 0);
    __builtin_amdgcn_s_setprio(0);
    __builtin_amdgcn_s_barrier();

    aRd0 ^= 65536; aRd1 ^= 65536; bRd0 ^= 65536; bRd1 ^= 65536; nxt ^= 65536;
  }
#undef STAGE_A
#undef STAGE_B

  // drain in-flight prefetch before reusing smem (epilogue staging region
  // overlaps buffer 0, which the last iteration's garbage stage targets)
  asm volatile("s_waitcnt vmcnt(0)" ::: "memory");
  __builtin_amdgcn_s_barrier();

  // ---- epilogue.  C/D layout: col=lane&15, row=q*4+r (verified m89/m91) ----
  if (OUT_F32) {
    float* C = (float*)Cv + (size_t)z * sC;
#pragma unroll
    for (int mi = 0; mi < 8; ++mi)
#pragma unroll
      for (int ni = 0; ni < 4; ++ni)
#pragma unroll
        for (int r = 0; r < 4; ++r) {
          const int row = bm0 + wm + (mi << 4) + (q << 2) + r;
          const int col = bn0 + wn + (ni << 4) + r16;
          C[((size_t)row << 10) + col] = acc[mi][ni][r] * alpha;
        }
  } else {
    // per-wave-private LDS staging -> full 128-B row stores
    float* reg = (float*)smem + (size_t)w * 1056;   // 16 x 66 floats
    uint16_t* C = (uint16_t*)Cv + (size_t)z * sC;
#pragma unroll
    for (int mi = 0; mi < 8; ++mi) {
#pragma unroll
      for (int ni = 0; ni < 4; ++ni)
#pragma unroll
        for (int r = 0; r < 4; ++r)
          reg[((q << 2) + r) * 66 + (ni << 4) + r16] = acc[mi][ni][r] * alpha;
#pragma unroll
      for (int it = 0; it < 8; ++it) {
        const int rr = (it << 1) + (lane >> 5);     // 0..15
        const int cc = (lane & 31) << 1;            // 0..62
        const float2 v = *(const float2*)(reg + rr * 66 + cc);
        const uint32_t p = (uint32_t)f2bf(v.x) | ((uint32_t)f2bf(v.y) << 16);
        const int row = bm0 + wm + (mi << 4) + rr;
        const int col = bn0 + wn + cc;
        *(uint32_t*)(C + ((size_t)row << 10) + col) = p;
      }
    }
  }
}

// dst[c][r] = (bf16) src[r][c]; src: R x C fp32 row-major.  32x32 LDS tiles.
__global__ __launch_bounds__(256)
void transpose_cast(const float* __restrict__ src, uint16_t* __restrict__ dst,
                    int R, int Ccols, size_t sStride, size_t dStride)
{
  __shared__ float tile[32][33];
  const int z = blockIdx.z;
  src += (size_t)z * sStride;
  dst += (size_t)z * dStride;
  const int c0 = blockIdx.x << 5;
  const int r0 = blockIdx.y << 5;
  const int tx = threadIdx.x;
  const int ty = threadIdx.y;
#pragma unroll
  for (int i = 0; i < 32; i += 8)
    tile[ty + i][tx] = src[(size_t)(r0 + ty + i) * Ccols + (c0 + tx)];
  __syncthreads();
#pragma unroll
  for (int i = 0; i < 32; i += 8)
    dst[(size_t)(c0 + ty + i) * R + (r0 + tx)] = f2bf(tile[tx][ty + i]);
}

// All three 1024x1024 weight transposes in one launch (z selects matrix).
__global__ __launch_bounds__(256)
void transpose_cast_w(const float* __restrict__ w0, const float* __restrict__ w1,
                      const float* __restrict__ w2, uint16_t* __restrict__ o0,
                      uint16_t* __restrict__ o1, uint16_t* __restrict__ o2)
{
  __shared__ float tile[32][33];
  const int z = blockIdx.z;
  const float* src = (z == 0) ? w0 : (z == 1) ? w1 : w2;
  uint16_t* dst = (z == 0) ? o0 : (z == 1) ? o1 : o2;
  const int c0 = blockIdx.x << 5;
  const int r0 = blockIdx.y << 5;
  const int tx = threadIdx.x;
  const int ty = threadIdx.y;
#pragma unroll
  for (int i = 0; i < 32; i += 8)
    tile[ty + i][tx] = src[(size_t)(r0 + ty + i) * 1024 + (c0 + tx)];
  __syncthreads();
#pragma unroll
  for (int i = 0; i < 32; i += 8)
    dst[(size_t)(c0 + ty + i) * 1024 + (r0 + tx)] = f2bf(tile[tx][ty + i]);
}

// row softmax over 1024 bf16 logits; one 256-thread block per row.
__global__ __launch_bounds__(256)
void softmax_rows(const uint16_t* __restrict__ in, uint16_t* __restrict__ out)
{
  const size_t row = blockIdx.x;
  const ushort4* p4 = (const ushort4*)(in + row * 1024);
  ushort4* o4 = (ushort4*)(out + row * 1024);
  const int t = threadIdx.x;
  const int lane = t & 63;
  const int wv = t >> 6;

  const ushort4 u = p4[t];
  float v0 = bf2f(u.x), v1 = bf2f(u.y), v2 = bf2f(u.z), v3 = bf2f(u.w);

  float m = fmaxf(fmaxf(v0, v1), fmaxf(v2, v3));
#pragma unroll
  for (int s = 32; s; s >>= 1) m = fmaxf(m, __shfl_xor(m, s, 64));
  __shared__ float red[8];
  if (lane == 0) red[wv] = m;
  __syncthreads();
  m = fmaxf(fmaxf(red[0], red[1]), fmaxf(red[2], red[3]));

  const float e0 = __expf(v0 - m), e1 = __expf(v1 - m);
  const float e2 = __expf(v2 - m), e3 = __expf(v3 - m);
  float s = e0 + e1 + e2 + e3;
#pragma unroll
  for (int sh = 32; sh; sh >>= 1) s += __shfl_xor(s, sh, 64);
  if (lane == 0) red[4 + wv] = s;
  __syncthreads();
  s = red[4] + red[5] + red[6] + red[7];

  const float inv = 1.0f / s;
  ushort4 r;
  r.x = f2bf(e0 * inv); r.y = f2bf(e1 * inv);
  r.z = f2bf(e2 * inv); r.w = f2bf(e3 * inv);
  o4[t] = r;
}

extern "C" void kernel_launch(void* const* d_in, const int* in_sizes, int n_in,
                              void* d_out, int out_size, void* d_ws, size_t ws_size,
                              hipStream_t stream)
{
  const float* x  = (const float*)d_in[0];
  const float* wk = (const float*)d_in[1];
  const float* wq = (const float*)d_in[2];
  const float* wv = (const float*)d_in[3];
  float* out = (float*)d_out;

  constexpr int BB = 16, N = 1024, D = 1024;
  constexpr size_t DN = (size_t)D * N;

  // workspace layout (bytes)            size    lifetime
  // xT   @ 0                            32 MB   dead after G3 -> reused as kq
  // Wtk  @ 32M, Wtq @ 34M, Wtv @ 36M     6 MB
  // vk   @ 38M                          32 MB   dead after G4 -> reused as sm
  // vq   @ 70M
  // vvT  @ 102M                         (total 134 MB)
  char* ws = (char*)d_ws;
  uint16_t* xT  = (uint16_t*)(ws);
  uint16_t* Wtk = (uint16_t*)(ws + (32ull << 20));
  uint16_t* Wtq = (uint16_t*)(ws + (34ull << 20));
  uint16_t* Wtv = (uint16_t*)(ws + (36ull << 20));
  uint16_t* vk  = (uint16_t*)(ws + (38ull << 20));
  uint16_t* vq  = (uint16_t*)(ws + (70ull << 20));
  uint16_t* vvT = (uint16_t*)(ws + (102ull << 20));
  uint16_t* kq  = xT;
  uint16_t* sm  = vk;

  const dim3 tb(32, 8);
  transpose_cast<<<dim3(D / 32, N / 32, BB), tb, 0, stream>>>(x, xT, N, D, DN, DN);
  transpose_cast_w<<<dim3(N / 32, N / 32, 3), tb, 0, stream>>>(wk, wq, wv,
                                                               Wtk, Wtq, Wtv);

  // vk[b][d][k] = sum_n xT[b][d][n] * Wtk[k][n]
  gemm_bt256<false><<<256, 512, 0, stream>>>(xT, Wtk, vk, DN, 0, DN, 1.0f);
  gemm_bt256<false><<<256, 512, 0, stream>>>(xT, Wtq, vq, DN, 0, DN, 1.0f);
  // vvT[b][n][d] = sum_n' Wtv[n][n'] * xT[b][d][n']
  gemm_bt256<false><<<256, 512, 0, stream>>>(Wtv, xT, vvT, 0, DN, DN, 1.0f);
  // kq[b][d][e] = (1/32) sum_n vk[b][d][n] * vq[b][e][n]
  gemm_bt256<false><<<256, 512, 0, stream>>>(vk, vq, kq, DN, DN, DN, 0.03125f);
  softmax_rows<<<BB * D, 256, 0, stream>>>(kq, sm);
  // out[b][n][d] = sum_e vvT[b][n][e] * sm[b][d][e]
  gemm_bt256<true><<<256, 512, 0, stream>>>(vvT, sm, out, DN, DN, DN, 1.0f);
}

// Round 2
// 301.302 us; speedup vs baseline: 1.1062x; 1.0509x over previous
//
#include <hip/hip_runtime.h>
#include <stdint.h>

// ---------------------------------------------------------------------------
// SelfAttention: out[b,n,d] = ( softmax( (X^T Wk)(X^T Wq)^T / 32 ) (X^T Wv) )^T
// B=16, N=D=1024.
//
// R5 algebra: kq = xT (Wk Wq^T) x.  Precompute W2T = Wq Wk^T (split-K GEMM,
//   ~free), then tmp = xT @ W2T^T-form, kq = tmp @ xT-form.  5 big GEMMs -> 4.
// R5 schedule: 8-phase 256x256 kernel keeps R4's stage/vmcnt skeleton but
//   pipelines fragment reads one phase ahead and drops all lgkmcnt(0) drains
//   (compiler emits counted lgkm for plain LDS loads).  No MFMA cluster waits
//   on reads issued in its own phase:
//     P1: MFMA(m0,nA: afa,bA)   reads bfB   (Bb(t) proven by P1 vmcnt(4))
//     P2: MFMA(m0,nB: afa,bB)   reads afb   (Ab(t) proven by P2 vmcnt(4))
//     P3: MFMA(m1,nB: afb,bB)   no reads
//     P4: MFMA(m1,nA: afb,bA)   then prefetch afa,bA of t+1 from nxt
//         (Aa,Ba(t+1) proven by P4 vmcnt(4); LDS ranges disjoint from
//          in-flight Bb/Ab stage writes)
//   vmcnt invariants identical to R4 (never 0 in-loop).
// ---------------------------------------------------------------------------

typedef __bf16 bf16x8_t __attribute__((ext_vector_type(8)));
typedef float  f32x4_t  __attribute__((ext_vector_type(4)));

typedef __attribute__((address_space(3))) uint32_t as3_u32;
typedef __attribute__((address_space(1))) uint32_t as1_u32;

__device__ __forceinline__ void async_copy16(const void* g, const void* l) {
  __builtin_amdgcn_global_load_lds((const as1_u32*)(uintptr_t)g,
                                   (as3_u32*)(uint32_t)(uintptr_t)l,
                                   16, 0, 0);
}

__device__ __forceinline__ uint16_t f2bf(float f) {  // RNE
  uint32_t x = __float_as_uint(f);
  return (uint16_t)((x + 0x7fffu + ((x >> 16) & 1u)) >> 16);
}
__device__ __forceinline__ float bf2f(uint16_t b) {
  return __uint_as_float(((uint32_t)b) << 16);
}

// C[m,n] = alpha * sum_k A[m,k] * B[n,k].  M=N=K=1024 fixed.  256 blocks x 512.
template <bool OUT_F32>
__global__ __launch_bounds__(512, 2)
void gemm_bt256(const uint16_t* __restrict__ A, const uint16_t* __restrict__ B,
                void* __restrict__ Cv, size_t sA, size_t sB, size_t sC,
                float alpha)
{
  __shared__ __align__(16) char smem[131072];

  // ---- XCD-aware swizzle: lid%8 = XCD; 2 batches per XCD, 4x4 tiles/batch --
  const int lid  = blockIdx.x;
  const int xcd  = lid & 7;
  const int slot = lid >> 3;            // 0..31
  const int z    = (xcd << 1) | (slot >> 4);
  const int t16  = slot & 15;
  const int bm0  = (t16 >> 2) << 8;
  const int bn0  = (t16 & 3) << 8;

  A += (size_t)z * sA + ((size_t)bm0 << 10);
  B += (size_t)z * sB + ((size_t)bn0 << 10);

  const int t    = threadIdx.x;
  const int lane = t & 63;
  const int w    = t >> 6;
  const int q    = lane >> 4;
  const int r16  = lane & 15;
  const int wm   = (w >> 2) << 7;       // 0,128
  const int wn   = (w & 3) << 6;        // 0,64,128,192

  // ---- staging per-thread constants (XOR-chunk swizzled source) ----
  const int g0  = t >> 3;               // 0..63
  const int cp  = t & 7;                // LDS chunk slot
  const int ce  = (cp ^ (g0 & 7)) << 3; // logical k-chunk elem offset
  const int sAo = (g0 << 7) + (cp << 4);
  const int rB  = ((g0 >> 5) << 6) + (g0 & 31);
  const int sBo = (rB << 7) + (cp << 4);
  const uint16_t* Ab = A + ((size_t)g0 << 10) + ce;
  const uint16_t* Bb = B + ((size_t)rB << 10) + ce;

  // A set s (s=0 rows {0-63,128-191}, s=1 rows {64-127,192-255}): 2 loads.
#define STAGE_A(s, kge, dst) do {                                              \
    async_copy16(Ab + (((s)*64 +   0) << 10) + (kge),                          \
                 smem + (dst) + sAo + (s)*8192);                               \
    async_copy16(Ab + (((s)*64 + 128) << 10) + (kge),                          \
                 smem + (dst) + sAo + (s)*8192 + 16384);                       \
  } while (0)
  // B set s (s=0 rows {0-31,64-95,128-159,192-223}, s=1 those +32): 2 loads.
#define STAGE_B(s, kge, dst) do {                                              \
    async_copy16(Bb + (((s)*32 +   0) << 10) + (kge),                          \
                 smem + (dst) + 32768 + sBo + (s)*4096);                       \
    async_copy16(Bb + (((s)*32 + 128) << 10) + (kge),                          \
                 smem + (dst) + 32768 + sBo + (s)*4096 + 16384);               \
  } while (0)

  // ---- fragment read bases (buffer 0); row&7 == r16&7 for all mi/wm ----
  const int sl0 = ((0 + q) ^ (r16 & 7)) << 4;
  const int sl1 = ((4 + q) ^ (r16 & 7)) << 4;
  int aRd0 = ((wm + r16) << 7) + sl0;
  int aRd1 = ((wm + r16) << 7) + sl1;
  int bRd0 = 32768 + ((wn + r16) << 7) + sl0;
  int bRd1 = 32768 + ((wn + r16) << 7) + sl1;

  f32x4_t acc[8][4];
#pragma unroll
  for (int i = 0; i < 8; i++)
#pragma unroll
    for (int j = 0; j < 4; j++) acc[i][j] = (f32x4_t){0.f, 0.f, 0.f, 0.f};

  bf16x8_t afa[4][2], afb[4][2], bA[2][2], bB[2][2];

  // ---- prologue: stage tile 0 into buffer 0 (order Aa, Ba, Bb, Ab) ----
  STAGE_A(0, 0, 0);
  STAGE_B(0, 0, 0);
  STAGE_B(1, 0, 0);
  STAGE_A(1, 0, 0);
  asm volatile("s_waitcnt vmcnt(4)" ::: "memory");   // Aa(0), Ba(0) done
  __builtin_amdgcn_s_barrier();
#pragma unroll
  for (int mi = 0; mi < 4; ++mi) {
    afa[mi][0] = *(const bf16x8_t*)(smem + aRd0 + mi * 2048);
    afa[mi][1] = *(const bf16x8_t*)(smem + aRd1 + mi * 2048);
  }
#pragma unroll
  for (int ni = 0; ni < 2; ++ni) {
    bA[ni][0] = *(const bf16x8_t*)(smem + bRd0 + ni * 2048);
    bA[ni][1] = *(const bf16x8_t*)(smem + bRd1 + ni * 2048);
  }

  int nxt = 65536;
  for (int t0 = 0; t0 < 16; ++t0) {
    const int kge = ((t0 + 1) & 15) << 6;   // t0=15 wraps: garbage, unread

    // ===== P1: MFMA (m0,nA) [afa,bA]; read bfB for P2 =====
    STAGE_A(0, kge, nxt);
    // outstanding [Bb(t),Ab(t),Aa(t+1)]=6 -> Bb(t) done
    asm volatile("s_waitcnt vmcnt(4)" ::: "memory");
    __builtin_amdgcn_s_barrier();
#pragma unroll
    for (int ni = 0; ni < 2; ++ni) {
      bB[ni][0] = *(const bf16x8_t*)(smem + bRd0 + 4096 + ni * 2048);
      bB[ni][1] = *(const bf16x8_t*)(smem + bRd1 + 4096 + ni * 2048);
    }
    __builtin_amdgcn_s_setprio(1);
#pragma unroll
    for (int kk = 0; kk < 2; ++kk)
#pragma unroll
      for (int mi = 0; mi < 4; ++mi)
#pragma unroll
        for (int ni = 0; ni < 2; ++ni)
          acc[mi][ni] = __builtin_amdgcn_mfma_f32_16x16x32_bf16(
              afa[mi][kk], bA[ni][kk], acc[mi][ni], 0, 0, 0);
    __builtin_amdgcn_s_setprio(0);
    __builtin_amdgcn_s_barrier();

    // ===== P2: MFMA (m0,nB) [afa,bB]; read afb for P3 =====
    STAGE_B(0, kge, nxt);
    // outstanding [Ab(t),Aa(t+1),Ba(t+1)]=6 -> Ab(t) done
    asm volatile("s_waitcnt vmcnt(4)" ::: "memory");
    __builtin_amdgcn_s_barrier();
#pragma unroll
    for (int mi = 0; mi < 4; ++mi) {
      afb[mi][0] = *(const bf16x8_t*)(smem + aRd0 + 8192 + mi * 2048);
      afb[mi][1] = *(const bf16x8_t*)(smem + aRd1 + 8192 + mi * 2048);
    }
    __builtin_amdgcn_s_setprio(1);
#pragma unroll
    for (int kk = 0; kk < 2; ++kk)
#pragma unroll
      for (int mi = 0; mi < 4; ++mi)
#pragma unroll
        for (int ni = 0; ni < 2; ++ni)
          acc[mi][2 + ni] = __builtin_amdgcn_mfma_f32_16x16x32_bf16(
              afa[mi][kk], bB[ni][kk], acc[mi][2 + ni], 0, 0, 0);
    __builtin_amdgcn_s_setprio(0);
    __builtin_amdgcn_s_barrier();

    // ===== P3: MFMA (m1,nB) [afb,bB]; no reads =====
    STAGE_B(1, kge, nxt);
    __builtin_amdgcn_s_barrier();
    __builtin_amdgcn_s_setprio(1);
#pragma unroll
    for (int kk = 0; kk < 2; ++kk)
#pragma unroll
      for (int mi = 0; mi < 4; ++mi)
#pragma unroll
        for (int ni = 0; ni < 2; ++ni)
          acc[4 + mi][2 + ni] = __builtin_amdgcn_mfma_f32_16x16x32_bf16(
              afb[mi][kk], bB[ni][kk], acc[4 + mi][2 + ni], 0, 0, 0);
    __builtin_amdgcn_s_setprio(0);
    __builtin_amdgcn_s_barrier();

    // ===== P4: MFMA (m1,nA) [afb,bA]; then prefetch afa,bA of t+1 =====
    STAGE_A(1, kge, nxt);
    // outstanding [Aa,Ba,Bb,Ab](t+1)=8 -> Aa(t+1), Ba(t+1) done
    asm volatile("s_waitcnt vmcnt(4)" ::: "memory");
    __builtin_amdgcn_s_barrier();
    __builtin_amdgcn_s_setprio(1);
#pragma unroll
    for (int kk = 0; kk < 2; ++kk)
#pragma unroll
      for (int mi = 0; mi < 4; ++mi)
#pragma unroll
        for (int ni = 0; ni < 2; ++ni)
          acc[4 + mi][ni] = __builtin_amdgcn_mfma_f32_16x16x32_bf16(
              afb[mi][kk], bA[ni][kk], acc[4 + mi][ni], 0, 0, 0);
    __builtin_amdgcn_s_setprio(0);
    // prefetch next tile's (afa,bA) from nxt buffer (disjoint from in-flight
    // Bb/Ab stage regions; Aa,Ba staged per vmcnt above)
#pragma unroll
    for (int mi = 0; mi < 4; ++mi) {
      afa[mi][0] = *(const bf16x8_t*)(smem + (aRd0 ^ 65536) + mi * 2048);
      afa[mi][1] = *(const bf16x8_t*)(smem + (aRd1 ^ 65536) + mi * 2048);
    }
#pragma unroll
    for (int ni = 0; ni < 2; ++ni) {
      bA[ni][0] = *(const bf16x8_t*)(smem + (bRd0 ^ 65536) + ni * 2048);
      bA[ni][1] = *(const bf16x8_t*)(smem + (bRd1 ^ 65536) + ni * 2048);
    }
    __builtin_amdgcn_s_barrier();

    aRd0 ^= 65536; aRd1 ^= 65536; bRd0 ^= 65536; bRd1 ^= 65536; nxt ^= 65536;
  }
#undef STAGE_A
#undef STAGE_B

  // drain in-flight prefetch before reusing smem for the epilogue
  asm volatile("s_waitcnt vmcnt(0)" ::: "memory");
  __builtin_amdgcn_s_barrier();

  // ---- epilogue.  C/D layout: col=lane&15, row=q*4+r (verified m89/m91) ----
  if (OUT_F32) {
    float* C = (float*)Cv + (size_t)z * sC;
#pragma unroll
    for (int mi = 0; mi < 8; ++mi)
#pragma unroll
      for (int ni = 0; ni < 4; ++ni)
#pragma unroll
        for (int r = 0; r < 4; ++r) {
          const int row = bm0 + wm + (mi << 4) + (q << 2) + r;
          const int col = bn0 + wn + (ni << 4) + r16;
          C[((size_t)row << 10) + col] = acc[mi][ni][r] * alpha;
        }
  } else {
    // per-wave-private LDS staging -> full 128-B row stores
    float* reg = (float*)smem + (size_t)w * 1056;   // 16 x 66 floats
    uint16_t* C = (uint16_t*)Cv + (size_t)z * sC;
#pragma unroll
    for (int mi = 0; mi < 8; ++mi) {
#pragma unroll
      for (int ni = 0; ni < 4; ++ni)
#pragma unroll
        for (int r = 0; r < 4; ++r)
          reg[((q << 2) + r) * 66 + (ni << 4) + r16] = acc[mi][ni][r] * alpha;
#pragma unroll
      for (int it = 0; it < 8; ++it) {
        const int rr = (it << 1) + (lane >> 5);     // 0..15
        const int cc = (lane & 31) << 1;            // 0..62
        const float2 v = *(const float2*)(reg + rr * 66 + cc);
        const uint32_t p = (uint32_t)f2bf(v.x) | ((uint32_t)f2bf(v.y) << 16);
        const int row = bm0 + wm + (mi << 4) + rr;
        const int col = bn0 + wn + cc;
        *(uint32_t*)(C + ((size_t)row << 10) + col) = p;
      }
    }
  }
}

// Split-K GEMM for W2T = Wq Wk^T: P[slice][m,n] = sum_{k in slice} A[m,k]B[n,k]
// M=N=1024, K=1024, splitK=4 (256 k each).  grid 256 x 256thr.  R3's proven
// 128x128 body (XOR-chunk LDS), f32 partial output.
__global__ __launch_bounds__(256, 4)
void gemm128_splitk(const uint16_t* __restrict__ A, const uint16_t* __restrict__ B,
                    float* __restrict__ P)
{
  __shared__ __align__(16) char smem[32768];
  char* As = smem;
  char* Bs = smem + 16384;

  const int slice = blockIdx.x >> 6;
  const int tile  = blockIdx.x & 63;
  const int bm0   = (tile >> 3) << 7;
  const int bn0   = (tile & 7) << 7;
  const int koff  = slice << 8;

  const int t    = threadIdx.x;
  const int lane = t & 63;
  const int w    = t >> 6;
  const int q    = lane >> 4;
  const int r16  = lane & 15;
  const int wm   = (w >> 1) << 6;
  const int wn   = (w & 1) << 6;

  f32x4_t acc[4][4];
#pragma unroll
  for (int i = 0; i < 4; i++)
#pragma unroll
    for (int j = 0; j < 4; j++) acc[i][j] = (f32x4_t){0.f, 0.f, 0.f, 0.f};

  for (int k0 = koff; k0 < koff + 256; k0 += 64) {
#pragma unroll
    for (int i = 0; i < 4; i++) {
      const int o  = (i << 12) + (t << 4);
      const int m  = o >> 7;
      const int cp = (o >> 4) & 7;
      const int c  = cp ^ (m & 7);
      async_copy16(A + (size_t)(bm0 + m) * 1024 + (size_t)(k0 + (c << 3)), As + o);
      async_copy16(B + (size_t)(bn0 + m) * 1024 + (size_t)(k0 + (c << 3)), Bs + o);
    }
    __syncthreads();
#pragma unroll
    for (int kk = 0; kk < 2; kk++) {
      bf16x8_t af[4], bfr[4];
#pragma unroll
      for (int mi = 0; mi < 4; mi++) {
        const int m = wm + (mi << 4) + r16;
        const int c = (kk << 2) + q;
        af[mi] = *(const bf16x8_t*)(As + (m << 7) + ((c ^ (m & 7)) << 4));
      }
#pragma unroll
      for (int ni = 0; ni < 4; ni++) {
        const int n = wn + (ni << 4) + r16;
        const int c = (kk << 2) + q;
        bfr[ni] = *(const bf16x8_t*)(Bs + (n << 7) + ((c ^ (n & 7)) << 4));
      }
#pragma unroll
      for (int mi = 0; mi < 4; mi++)
#pragma unroll
        for (int ni = 0; ni < 4; ni++)
          acc[mi][ni] = __builtin_amdgcn_mfma_f32_16x16x32_bf16(
              af[mi], bfr[ni], acc[mi][ni], 0, 0, 0);
    }
    __syncthreads();
  }

  float* C = P + (size_t)slice * (1024u * 1024u);
#pragma unroll
  for (int mi = 0; mi < 4; mi++)
#pragma unroll
    for (int ni = 0; ni < 4; ni++)
#pragma unroll
      for (int r = 0; r < 4; r++) {
        const int row = bm0 + wm + (mi << 4) + (q << 2) + r;
        const int col = bn0 + wn + (ni << 4) + r16;
        C[((size_t)row << 10) + col] = acc[mi][ni][r];
      }
}

// W2Tc = bf16( P[0] + P[1] + P[2] + P[3] ).  grid 1024 x 256thr, 4 elems/thr.
__global__ __launch_bounds__(256)
void reduce_w2t(const float* __restrict__ P, uint16_t* __restrict__ W)
{
  const size_t i4 = (((size_t)blockIdx.x << 8) + threadIdx.x) << 2;
  const float4 a = *(const float4*)(P + i4);
  const float4 b = *(const float4*)(P + (1u << 20) + i4);
  const float4 c = *(const float4*)(P + (2u << 20) + i4);
  const float4 d = *(const float4*)(P + (3u << 20) + i4);
  ushort4 r;
  r.x = f2bf(a.x + b.x + c.x + d.x);
  r.y = f2bf(a.y + b.y + c.y + d.y);
  r.z = f2bf(a.z + b.z + c.z + d.z);
  r.w = f2bf(a.w + b.w + c.w + d.w);
  *(ushort4*)(W + i4) = r;
}

// z=0: cast Wk->o0 (row-major); z=1: cast Wq->o1; z=2: transpose-cast Wv->o2.
__global__ __launch_bounds__(256)
void prep_w(const float* __restrict__ w0, const float* __restrict__ w1,
            const float* __restrict__ w2, uint16_t* __restrict__ o0,
            uint16_t* __restrict__ o1, uint16_t* __restrict__ o2)
{
  __shared__ float tile[32][33];
  const int z = blockIdx.z;
  const int c0 = blockIdx.x << 5;
  const int r0 = blockIdx.y << 5;
  const int tx = threadIdx.x;
  const int ty = threadIdx.y;
  if (z < 2) {
    const float* src = z ? w1 : w0;
    uint16_t* dst = z ? o1 : o0;
#pragma unroll
    for (int i = 0; i < 32; i += 8)
      dst[(size_t)(r0 + ty + i) * 1024 + (c0 + tx)] =
          f2bf(src[(size_t)(r0 + ty + i) * 1024 + (c0 + tx)]);
  } else {
#pragma unroll
    for (int i = 0; i < 32; i += 8)
      tile[ty + i][tx] = w2[(size_t)(r0 + ty + i) * 1024 + (c0 + tx)];
    __syncthreads();
#pragma unroll
    for (int i = 0; i < 32; i += 8)
      o2[(size_t)(c0 + ty + i) * 1024 + (r0 + tx)] = f2bf(tile[tx][ty + i]);
  }
}

// dst[c][r] = (bf16) src[r][c]; src: R x C fp32 row-major.  32x32 LDS tiles.
__global__ __launch_bounds__(256)
void transpose_cast(const float* __restrict__ src, uint16_t* __restrict__ dst,
                    int R, int Ccols, size_t sStride, size_t dStride)
{
  __shared__ float tile[32][33];
  const int z = blockIdx.z;
  src += (size_t)z * sStride;
  dst += (size_t)z * dStride;
  const int c0 = blockIdx.x << 5;
  const int r0 = blockIdx.y << 5;
  const int tx = threadIdx.x;
  const int ty = threadIdx.y;
#pragma unroll
  for (int i = 0; i < 32; i += 8)
    tile[ty + i][tx] = src[(size_t)(r0 + ty + i) * Ccols + (c0 + tx)];
  __syncthreads();
#pragma unroll
  for (int i = 0; i < 32; i += 8)
    dst[(size_t)(c0 + ty + i) * R + (r0 + tx)] = f2bf(tile[tx][ty + i]);
}

// row softmax over 1024 bf16 logits; one 256-thread block per row.
__global__ __launch_bounds__(256)
void softmax_rows(const uint16_t* __restrict__ in, uint16_t* __restrict__ out)
{
  const size_t row = blockIdx.x;
  const ushort4* p4 = (const ushort4*)(in + row * 1024);
  ushort4* o4 = (ushort4*)(out + row * 1024);
  const int t = threadIdx.x;
  const int lane = t & 63;
  const int wv = t >> 6;

  const ushort4 u = p4[t];
  float v0 = bf2f(u.x), v1 = bf2f(u.y), v2 = bf2f(u.z), v3 = bf2f(u.w);

  float m = fmaxf(fmaxf(v0, v1), fmaxf(v2, v3));
#pragma unroll
  for (int s = 32; s; s >>= 1) m = fmaxf(m, __shfl_xor(m, s, 64));
  __shared__ float red[8];
  if (lane == 0) red[wv] = m;
  __syncthreads();
  m = fmaxf(fmaxf(red[0], red[1]), fmaxf(red[2], red[3]));

  const float e0 = __expf(v0 - m), e1 = __expf(v1 - m);
  const float e2 = __expf(v2 - m), e3 = __expf(v3 - m);
  float s = e0 + e1 + e2 + e3;
#pragma unroll
  for (int sh = 32; sh; sh >>= 1) s += __shfl_xor(s, sh, 64);
  if (lane == 0) red[4 + wv] = s;
  __syncthreads();
  s = red[4] + red[5] + red[6] + red[7];

  const float inv = 1.0f / s;
  ushort4 r;
  r.x = f2bf(e0 * inv); r.y = f2bf(e1 * inv);
  r.z = f2bf(e2 * inv); r.w = f2bf(e3 * inv);
  o4[t] = r;
}

extern "C" void kernel_launch(void* const* d_in, const int* in_sizes, int n_in,
                              void* d_out, int out_size, void* d_ws, size_t ws_size,
                              hipStream_t stream)
{
  const float* x  = (const float*)d_in[0];
  const float* wk = (const float*)d_in[1];
  const float* wq = (const float*)d_in[2];
  const float* wv = (const float*)d_in[3];
  float* out = (float*)d_out;

  constexpr int BB = 16, N = 1024, D = 1024;
  constexpr size_t DN = (size_t)D * N;

  // workspace layout (bytes)           size    lifetime
  // xT    @ 0                          32 MB   through kq gemm
  // Wkc   @ 32M, Wqc @ 34M, Wtv @ 36M   6 MB
  // W2Tc  @ 38M                         2 MB   dead after tmp gemm
  // W2p   @ 40M                        16 MB   dead after reduce
  // tmp   @ 56M                        32 MB   dead after kq gemm -> sm
  // vvT   @ 88M                        32 MB
  // kq    @ 120M                       32 MB   (total 152 MB; ws = 256 MiB)
  char* ws = (char*)d_ws;
  uint16_t* xT   = (uint16_t*)(ws);
  uint16_t* Wkc  = (uint16_t*)(ws + (32ull << 20));
  uint16_t* Wqc  = (uint16_t*)(ws + (34ull << 20));
  uint16_t* Wtv  = (uint16_t*)(ws + (36ull << 20));
  uint16_t* W2Tc = (uint16_t*)(ws + (38ull << 20));
  float*    W2p  = (float*)   (ws + (40ull << 20));
  uint16_t* tmp  = (uint16_t*)(ws + (56ull << 20));
  uint16_t* vvT  = (uint16_t*)(ws + (88ull << 20));
  uint16_t* kq   = (uint16_t*)(ws + (120ull << 20));
  uint16_t* sm   = tmp;

  const dim3 tb(32, 8);
  // weights: cast Wk, Wq; transpose-cast Wv
  prep_w<<<dim3(N / 32, N / 32, 3), tb, 0, stream>>>(wk, wq, wv, Wkc, Wqc, Wtv);
  // W2T[j,i] = sum_n Wq[j,n] Wk[i,n]  (split-K=4 partials, then reduce+cast)
  gemm128_splitk<<<256, 256, 0, stream>>>(Wqc, Wkc, W2p);
  reduce_w2t<<<1024, 256, 0, stream>>>(W2p, W2Tc);
  // xT[b][d][n] = x[b][n][d]
  transpose_cast<<<dim3(D / 32, N / 32, BB), tb, 0, stream>>>(x, xT, N, D, DN, DN);
  // tmp[b][d][j] = sum_i xT[b][d][i] * W2T[j][i]
  gemm_bt256<false><<<256, 512, 0, stream>>>(xT, W2Tc, tmp, DN, 0, DN, 1.0f);
  // vvT[b][n][d] = sum_n' Wtv[n][n'] * xT[b][d][n']
  gemm_bt256<false><<<256, 512, 0, stream>>>(Wtv, xT, vvT, 0, DN, DN, 1.0f);
  // kq[b][d][e] = (1/32) sum_j tmp[b][d][j] * xT[b][e][j]
  gemm_bt256<false><<<256, 512, 0, stream>>>(tmp, xT, kq, DN, DN, DN, 0.03125f);
  softmax_rows<<<BB * D, 256, 0, stream>>>(kq, sm);
  // out[b][n][d] = sum_e vvT[b][n][e] * sm[b][d][e]
  gemm_bt256<true><<<256, 512, 0, stream>>>(vvT, sm, out, DN, DN, DN, 1.0f);
}

// Round 3
// 291.733 us; speedup vs baseline: 1.1425x; 1.0328x over previous
//
#include <hip/hip_runtime.h>
#include <stdint.h>

// ---------------------------------------------------------------------------
// SelfAttention: out[b,n,d] = ( softmax( (X^T Wk)(X^T Wq)^T / 32 ) (X^T Wv) )^T
// B=16, N=D=1024.
//
// R5 algebra: kq = xT (Wk Wq^T) x -> 4 big GEMMs (tmp, vvT, kq, out).
// R6a fusion: softmax eliminated.  kq-GEMM epilogue (EPI=2) writes
//   P = exp(kq/32) bf16 + 16-slot/row f32 partial sums Spart (deterministic,
//   no atomics).  Final GEMM (EPI=3) sums the 16 partials per output column
//   and scales by 1/S.  No max-subtraction: |kq| <~ 13 -> e^13 f32-safe;
//   P bf16 rel err 0.4% == old bf16 sm path.
// R6b schedule: staging front-loaded: P1 issues {Aa,Ba}(t+1) (4 gll),
//   P2 issues {Bb,Ab}(t+1) (4 gll), P3/P4 none.  TWO vmcnt waits per K-tile
//   (was 3), both proving sets issued 3 phases earlier:
//     per-thread ledger (2 gll per set, vmcnt retires in issue order):
//     P1 entry: [Bb(t),Ab(t)]=4; +Aa,Ba(t+1) -> 8; wait vmcnt(4)
//               -> Bb(t),Ab(t) done (issued prev-P2, 3 phases ago)
//     P2: +Bb,Ab(t+1) -> 8; no wait (Ab(t) proven at P1)
//     P3: no stage, no wait
//     P4: wait vmcnt(4) -> Aa,Ba(t+1) done (issued P1, 3 phases ago);
//         after MFMA, prefetch-read afa,bA(t+1) from nxt (disjoint from
//         in-flight Bb,Ab(t+1) DMA regions)
//   wait->barrier->read ordering everywhere (vmcnt is per-wave; barrier
//   globalizes).  Never vmcnt(0) in-loop.
// ---------------------------------------------------------------------------

typedef __bf16 bf16x8_t __attribute__((ext_vector_type(8)));
typedef float  f32x4_t  __attribute__((ext_vector_type(4)));

typedef __attribute__((address_space(3))) uint32_t as3_u32;
typedef __attribute__((address_space(1))) uint32_t as1_u32;

__device__ __forceinline__ void async_copy16(const void* g, const void* l) {
  __builtin_amdgcn_global_load_lds((const as1_u32*)(uintptr_t)g,
                                   (as3_u32*)(uint32_t)(uintptr_t)l,
                                   16, 0, 0);
}

__device__ __forceinline__ uint16_t f2bf(float f) {  // RNE
  uint32_t x = __float_as_uint(f);
  return (uint16_t)((x + 0x7fffu + ((x >> 16) & 1u)) >> 16);
}
__device__ __forceinline__ float bf2f(uint16_t b) {
  return __uint_as_float(((uint32_t)b) << 16);
}

// C[m,n] = alpha * sum_k A[m,k] * B[n,k].  M=N=K=1024 fixed.  256 blocks x 512.
// EPI: 0 = bf16 C*alpha;  2 = bf16 exp(C*alpha) + Spart row partials;
//      3 = f32 C*alpha/S[col] (S = sum of 16 Spart slots).
template <int EPI>
__global__ __launch_bounds__(512, 2)
void gemm_bt256(const uint16_t* __restrict__ A, const uint16_t* __restrict__ B,
                void* __restrict__ Cv, size_t sA, size_t sB, size_t sC,
                float alpha, float* __restrict__ Sp)
{
  __shared__ __align__(16) char smem[131072];

  // ---- XCD-aware swizzle: lid%8 = XCD; 2 batches per XCD, 4x4 tiles/batch --
  const int lid  = blockIdx.x;
  const int xcd  = lid & 7;
  const int slot = lid >> 3;            // 0..31
  const int z    = (xcd << 1) | (slot >> 4);
  const int t16  = slot & 15;
  const int bm0  = (t16 >> 2) << 8;
  const int bn0  = (t16 & 3) << 8;

  A += (size_t)z * sA + ((size_t)bm0 << 10);
  B += (size_t)z * sB + ((size_t)bn0 << 10);

  const int t    = threadIdx.x;
  const int lane = t & 63;
  const int w    = t >> 6;
  const int q    = lane >> 4;
  const int r16  = lane & 15;
  const int wm   = (w >> 2) << 7;       // 0,128
  const int wn   = (w & 3) << 6;        // 0,64,128,192

  // ---- staging per-thread constants (XOR-chunk swizzled source) ----
  const int g0  = t >> 3;               // 0..63
  const int cp  = t & 7;                // LDS chunk slot
  const int ce  = (cp ^ (g0 & 7)) << 3; // logical k-chunk elem offset
  const int sAo = (g0 << 7) + (cp << 4);
  const int rB  = ((g0 >> 5) << 6) + (g0 & 31);
  const int sBo = (rB << 7) + (cp << 4);
  const uint16_t* Ab = A + ((size_t)g0 << 10) + ce;
  const uint16_t* Bb = B + ((size_t)rB << 10) + ce;

  // A set s (s=0 rows {0-63,128-191}, s=1 rows {64-127,192-255}): 2 loads.
#define STAGE_A(s, kge, dst) do {                                              \
    async_copy16(Ab + (((s)*64 +   0) << 10) + (kge),                          \
                 smem + (dst) + sAo + (s)*8192);                               \
    async_copy16(Ab + (((s)*64 + 128) << 10) + (kge),                          \
                 smem + (dst) + sAo + (s)*8192 + 16384);                       \
  } while (0)
  // B set s (s=0 rows {0-31,64-95,128-159,192-223}, s=1 those +32): 2 loads.
#define STAGE_B(s, kge, dst) do {                                              \
    async_copy16(Bb + (((s)*32 +   0) << 10) + (kge),                          \
                 smem + (dst) + 32768 + sBo + (s)*4096);                       \
    async_copy16(Bb + (((s)*32 + 128) << 10) + (kge),                          \
                 smem + (dst) + 32768 + sBo + (s)*4096 + 16384);               \
  } while (0)

  // ---- fragment read bases (buffer 0); row&7 == r16&7 for all mi/wm ----
  const int sl0 = ((0 + q) ^ (r16 & 7)) << 4;
  const int sl1 = ((4 + q) ^ (r16 & 7)) << 4;
  int aRd0 = ((wm + r16) << 7) + sl0;
  int aRd1 = ((wm + r16) << 7) + sl1;
  int bRd0 = 32768 + ((wn + r16) << 7) + sl0;
  int bRd1 = 32768 + ((wn + r16) << 7) + sl1;

  f32x4_t acc[8][4];
#pragma unroll
  for (int i = 0; i < 8; i++)
#pragma unroll
    for (int j = 0; j < 4; j++) acc[i][j] = (f32x4_t){0.f, 0.f, 0.f, 0.f};

  bf16x8_t afa[4][2], afb[4][2], bA[2][2], bB[2][2];

  // ---- prologue: stage tile 0 into buffer 0 (issue order Aa, Ba, Bb, Ab) --
  STAGE_A(0, 0, 0);
  STAGE_B(0, 0, 0);
  STAGE_B(1, 0, 0);
  STAGE_A(1, 0, 0);
  asm volatile("s_waitcnt vmcnt(4)" ::: "memory");   // Aa(0), Ba(0) done
  __builtin_amdgcn_s_barrier();
#pragma unroll
  for (int mi = 0; mi < 4; ++mi) {
    afa[mi][0] = *(const bf16x8_t*)(smem + aRd0 + mi * 2048);
    afa[mi][1] = *(const bf16x8_t*)(smem + aRd1 + mi * 2048);
  }
#pragma unroll
  for (int ni = 0; ni < 2; ++ni) {
    bA[ni][0] = *(const bf16x8_t*)(smem + bRd0 + ni * 2048);
    bA[ni][1] = *(const bf16x8_t*)(smem + bRd1 + ni * 2048);
  }

  int nxt = 65536;
  for (int t0 = 0; t0 < 16; ++t0) {
    const int kge = ((t0 + 1) & 15) << 6;   // t0=15 wraps: garbage, unread

    // ===== P1: stage Aa,Ba(t+1); wait Bb,Ab(t); MFMA (m0,nA); read bfB =====
    STAGE_A(0, kge, nxt);
    STAGE_B(0, kge, nxt);
    asm volatile("s_waitcnt vmcnt(4)" ::: "memory");  // Bb(t),Ab(t) done
    __builtin_amdgcn_s_barrier();
#pragma unroll
    for (int ni = 0; ni < 2; ++ni) {
      bB[ni][0] = *(const bf16x8_t*)(smem + bRd0 + 4096 + ni * 2048);
      bB[ni][1] = *(const bf16x8_t*)(smem + bRd1 + 4096 + ni * 2048);
    }
    __builtin_amdgcn_s_setprio(1);
#pragma unroll
    for (int kk = 0; kk < 2; ++kk)
#pragma unroll
      for (int mi = 0; mi < 4; ++mi)
#pragma unroll
        for (int ni = 0; ni < 2; ++ni)
          acc[mi][ni] = __builtin_amdgcn_mfma_f32_16x16x32_bf16(
              afa[mi][kk], bA[ni][kk], acc[mi][ni], 0, 0, 0);
    __builtin_amdgcn_s_setprio(0);
    __builtin_amdgcn_s_barrier();

    // ===== P2: stage Bb,Ab(t+1); MFMA (m0,nB); read afb =====
    STAGE_B(1, kge, nxt);
    STAGE_A(1, kge, nxt);
    __builtin_amdgcn_s_barrier();
#pragma unroll
    for (int mi = 0; mi < 4; ++mi) {
      afb[mi][0] = *(const bf16x8_t*)(smem + aRd0 + 8192 + mi * 2048);
      afb[mi][1] = *(const bf16x8_t*)(smem + aRd1 + 8192 + mi * 2048);
    }
    __builtin_amdgcn_s_setprio(1);
#pragma unroll
    for (int kk = 0; kk < 2; ++kk)
#pragma unroll
      for (int mi = 0; mi < 4; ++mi)
#pragma unroll
        for (int ni = 0; ni < 2; ++ni)
          acc[mi][2 + ni] = __builtin_amdgcn_mfma_f32_16x16x32_bf16(
              afa[mi][kk], bB[ni][kk], acc[mi][2 + ni], 0, 0, 0);
    __builtin_amdgcn_s_setprio(0);
    __builtin_amdgcn_s_barrier();

    // ===== P3: MFMA (m1,nB); no stage, no wait =====
    __builtin_amdgcn_s_barrier();
    __builtin_amdgcn_s_setprio(1);
#pragma unroll
    for (int kk = 0; kk < 2; ++kk)
#pragma unroll
      for (int mi = 0; mi < 4; ++mi)
#pragma unroll
        for (int ni = 0; ni < 2; ++ni)
          acc[4 + mi][2 + ni] = __builtin_amdgcn_mfma_f32_16x16x32_bf16(
              afb[mi][kk], bB[ni][kk], acc[4 + mi][2 + ni], 0, 0, 0);
    __builtin_amdgcn_s_setprio(0);
    __builtin_amdgcn_s_barrier();

    // ===== P4: wait Aa,Ba(t+1); MFMA (m1,nA); prefetch afa,bA(t+1) =====
    asm volatile("s_waitcnt vmcnt(4)" ::: "memory");  // Aa,Ba(t+1) done
    __builtin_amdgcn_s_barrier();
    __builtin_amdgcn_s_setprio(1);
#pragma unroll
    for (int kk = 0; kk < 2; ++kk)
#pragma unroll
      for (int mi = 0; mi < 4; ++mi)
#pragma unroll
        for (int ni = 0; ni < 2; ++ni)
          acc[4 + mi][ni] = __builtin_amdgcn_mfma_f32_16x16x32_bf16(
              afb[mi][kk], bA[ni][kk], acc[4 + mi][ni], 0, 0, 0);
    __builtin_amdgcn_s_setprio(0);
#pragma unroll
    for (int mi = 0; mi < 4; ++mi) {
      afa[mi][0] = *(const bf16x8_t*)(smem + (aRd0 ^ 65536) + mi * 2048);
      afa[mi][1] = *(const bf16x8_t*)(smem + (aRd1 ^ 65536) + mi * 2048);
    }
#pragma unroll
    for (int ni = 0; ni < 2; ++ni) {
      bA[ni][0] = *(const bf16x8_t*)(smem + (bRd0 ^ 65536) + ni * 2048);
      bA[ni][1] = *(const bf16x8_t*)(smem + (bRd1 ^ 65536) + ni * 2048);
    }
    __builtin_amdgcn_s_barrier();

    aRd0 ^= 65536; aRd1 ^= 65536; bRd0 ^= 65536; bRd1 ^= 65536; nxt ^= 65536;
  }
#undef STAGE_A
#undef STAGE_B

  // drain in-flight prefetch before reusing smem for the epilogue
  asm volatile("s_waitcnt vmcnt(0)" ::: "memory");
  __builtin_amdgcn_s_barrier();

  // ---- epilogue.  C/D layout: col=lane&15, row=q*4+r (verified m89/m91) ----
  if constexpr (EPI == 3) {
    // f32 out, scaled by 1/S[col]; S = sum of 16 Spart slots per column.
    float inv[4];
#pragma unroll
    for (int ni = 0; ni < 4; ++ni) {
      const int c = bn0 + wn + (ni << 4) + r16;
      float S = 0.f;
#pragma unroll
      for (int p = 0; p < 16; ++p)
        S += Sp[((size_t)p << 14) + ((size_t)z << 10) + c];
      inv[ni] = 1.0f / S;
    }
    float* C = (float*)Cv + (size_t)z * sC;
#pragma unroll
    for (int mi = 0; mi < 8; ++mi)
#pragma unroll
      for (int ni = 0; ni < 4; ++ni)
#pragma unroll
        for (int r = 0; r < 4; ++r) {
          const int row = bm0 + wm + (mi << 4) + (q << 2) + r;
          const int col = bn0 + wn + (ni << 4) + r16;
          C[((size_t)row << 10) + col] = acc[mi][ni][r] * alpha * inv[ni];
        }
  } else {
    // bf16 out via per-wave-private LDS staging -> full 128-B row stores.
    // EPI==2 additionally applies exp() and emits per-row partial sums.
    float* reg = (float*)smem + (size_t)w * 1056;   // 16 x 66 floats
    uint16_t* C = (uint16_t*)Cv + (size_t)z * sC;
    float* SpW = Sp + ((size_t)(((bn0 >> 8) << 2) + (w & 3)) << 14)
                    + ((size_t)z << 10);
#pragma unroll
    for (int mi = 0; mi < 8; ++mi) {
      if constexpr (EPI == 2) {
        float ev[4][4];
#pragma unroll
        for (int ni = 0; ni < 4; ++ni)
#pragma unroll
          for (int r = 0; r < 4; ++r) {
            ev[ni][r] = __expf(acc[mi][ni][r] * alpha);
            reg[((q << 2) + r) * 66 + (ni << 4) + r16] = ev[ni][r];
          }
#pragma unroll
        for (int r = 0; r < 4; ++r) {
          float s = ev[0][r] + ev[1][r] + ev[2][r] + ev[3][r];
          s += __shfl_xor(s, 1, 16);
          s += __shfl_xor(s, 2, 16);
          s += __shfl_xor(s, 4, 16);
          s += __shfl_xor(s, 8, 16);
          if (r16 == 0)
            SpW[bm0 + wm + (mi << 4) + (q << 2) + r] = s;
        }
      } else {
#pragma unroll
        for (int ni = 0; ni < 4; ++ni)
#pragma unroll
          for (int r = 0; r < 4; ++r)
            reg[((q << 2) + r) * 66 + (ni << 4) + r16] = acc[mi][ni][r] * alpha;
      }
#pragma unroll
      for (int it = 0; it < 8; ++it) {
        const int rr = (it << 1) + (lane >> 5);     // 0..15
        const int cc = (lane & 31) << 1;            // 0..62
        const float2 v = *(const float2*)(reg + rr * 66 + cc);
        const uint32_t p = (uint32_t)f2bf(v.x) | ((uint32_t)f2bf(v.y) << 16);
        const int row = bm0 + wm + (mi << 4) + rr;
        const int col = bn0 + wn + cc;
        *(uint32_t*)(C + ((size_t)row << 10) + col) = p;
      }
    }
  }
}

// Split-K GEMM for W2T = Wq Wk^T: P[slice][m,n] = sum_{k in slice} A[m,k]B[n,k]
// M=N=1024, K=1024, splitK=4 (256 k each).  grid 256 x 256thr.
__global__ __launch_bounds__(256, 4)
void gemm128_splitk(const uint16_t* __restrict__ A, const uint16_t* __restrict__ B,
                    float* __restrict__ P)
{
  __shared__ __align__(16) char smem[32768];
  char* As = smem;
  char* Bs = smem + 16384;

  const int slice = blockIdx.x >> 6;
  const int tile  = blockIdx.x & 63;
  const int bm0   = (tile >> 3) << 7;
  const int bn0   = (tile & 7) << 7;
  const int koff  = slice << 8;

  const int t    = threadIdx.x;
  const int lane = t & 63;
  const int w    = t >> 6;
  const int q    = lane >> 4;
  const int r16  = lane & 15;
  const int wm   = (w >> 1) << 6;
  const int wn   = (w & 1) << 6;

  f32x4_t acc[4][4];
#pragma unroll
  for (int i = 0; i < 4; i++)
#pragma unroll
    for (int j = 0; j < 4; j++) acc[i][j] = (f32x4_t){0.f, 0.f, 0.f, 0.f};

  for (int k0 = koff; k0 < koff + 256; k0 += 64) {
#pragma unroll
    for (int i = 0; i < 4; i++) {
      const int o  = (i << 12) + (t << 4);
      const int m  = o >> 7;
      const int cp = (o >> 4) & 7;
      const int c  = cp ^ (m & 7);
      async_copy16(A + (size_t)(bm0 + m) * 1024 + (size_t)(k0 + (c << 3)), As + o);
      async_copy16(B + (size_t)(bn0 + m) * 1024 + (size_t)(k0 + (c << 3)), Bs + o);
    }
    __syncthreads();
#pragma unroll
    for (int kk = 0; kk < 2; kk++) {
      bf16x8_t af[4], bfr[4];
#pragma unroll
      for (int mi = 0; mi < 4; mi++) {
        const int m = wm + (mi << 4) + r16;
        const int c = (kk << 2) + q;
        af[mi] = *(const bf16x8_t*)(As + (m << 7) + ((c ^ (m & 7)) << 4));
      }
#pragma unroll
      for (int ni = 0; ni < 4; ni++) {
        const int n = wn + (ni << 4) + r16;
        const int c = (kk << 2) + q;
        bfr[ni] = *(const bf16x8_t*)(Bs + (n << 7) + ((c ^ (n & 7)) << 4));
      }
#pragma unroll
      for (int mi = 0; mi < 4; mi++)
#pragma unroll
        for (int ni = 0; ni < 4; ni++)
          acc[mi][ni] = __builtin_amdgcn_mfma_f32_16x16x32_bf16(
              af[mi], bfr[ni], acc[mi][ni], 0, 0, 0);
    }
    __syncthreads();
  }

  float* C = P + (size_t)slice * (1024u * 1024u);
#pragma unroll
  for (int mi = 0; mi < 4; mi++)
#pragma unroll
    for (int ni = 0; ni < 4; ni++)
#pragma unroll
      for (int r = 0; r < 4; r++) {
        const int row = bm0 + wm + (mi << 4) + (q << 2) + r;
        const int col = bn0 + wn + (ni << 4) + r16;
        C[((size_t)row << 10) + col] = acc[mi][ni][r];
      }
}

// W2Tc = bf16( P[0] + P[1] + P[2] + P[3] ).  grid 1024 x 256thr, 4 elems/thr.
__global__ __launch_bounds__(256)
void reduce_w2t(const float* __restrict__ P, uint16_t* __restrict__ W)
{
  const size_t i4 = (((size_t)blockIdx.x << 8) + threadIdx.x) << 2;
  const float4 a = *(const float4*)(P + i4);
  const float4 b = *(const float4*)(P + (1u << 20) + i4);
  const float4 c = *(const float4*)(P + (2u << 20) + i4);
  const float4 d = *(const float4*)(P + (3u << 20) + i4);
  ushort4 r;
  r.x = f2bf(a.x + b.x + c.x + d.x);
  r.y = f2bf(a.y + b.y + c.y + d.y);
  r.z = f2bf(a.z + b.z + c.z + d.z);
  r.w = f2bf(a.w + b.w + c.w + d.w);
  *(ushort4*)(W + i4) = r;
}

// z=0: cast Wk->o0 (row-major); z=1: cast Wq->o1; z=2: transpose-cast Wv->o2.
__global__ __launch_bounds__(256)
void prep_w(const float* __restrict__ w0, const float* __restrict__ w1,
            const float* __restrict__ w2, uint16_t* __restrict__ o0,
            uint16_t* __restrict__ o1, uint16_t* __restrict__ o2)
{
  __shared__ float tile[32][33];
  const int z = blockIdx.z;
  const int c0 = blockIdx.x << 5;
  const int r0 = blockIdx.y << 5;
  const int tx = threadIdx.x;
  const int ty = threadIdx.y;
  if (z < 2) {
    const float* src = z ? w1 : w0;
    uint16_t* dst = z ? o1 : o0;
#pragma unroll
    for (int i = 0; i < 32; i += 8)
      dst[(size_t)(r0 + ty + i) * 1024 + (c0 + tx)] =
          f2bf(src[(size_t)(r0 + ty + i) * 1024 + (c0 + tx)]);
  } else {
#pragma unroll
    for (int i = 0; i < 32; i += 8)
      tile[ty + i][tx] = w2[(size_t)(r0 + ty + i) * 1024 + (c0 + tx)];
    __syncthreads();
#pragma unroll
    for (int i = 0; i < 32; i += 8)
      o2[(size_t)(c0 + ty + i) * 1024 + (r0 + tx)] = f2bf(tile[tx][ty + i]);
  }
}

// dst[c][r] = (bf16) src[r][c]; src: R x C fp32 row-major.  32x32 LDS tiles.
__global__ __launch_bounds__(256)
void transpose_cast(const float* __restrict__ src, uint16_t* __restrict__ dst,
                    int R, int Ccols, size_t sStride, size_t dStride)
{
  __shared__ float tile[32][33];
  const int z = blockIdx.z;
  src += (size_t)z * sStride;
  dst += (size_t)z * dStride;
  const int c0 = blockIdx.x << 5;
  const int r0 = blockIdx.y << 5;
  const int tx = threadIdx.x;
  const int ty = threadIdx.y;
#pragma unroll
  for (int i = 0; i < 32; i += 8)
    tile[ty + i][tx] = src[(size_t)(r0 + ty + i) * Ccols + (c0 + tx)];
  __syncthreads();
#pragma unroll
  for (int i = 0; i < 32; i += 8)
    dst[(size_t)(c0 + ty + i) * R + (r0 + tx)] = f2bf(tile[tx][ty + i]);
}

extern "C" void kernel_launch(void* const* d_in, const int* in_sizes, int n_in,
                              void* d_out, int out_size, void* d_ws, size_t ws_size,
                              hipStream_t stream)
{
  const float* x  = (const float*)d_in[0];
  const float* wk = (const float*)d_in[1];
  const float* wq = (const float*)d_in[2];
  const float* wv = (const float*)d_in[3];
  float* out = (float*)d_out;

  constexpr int BB = 16, N = 1024, D = 1024;
  constexpr size_t DN = (size_t)D * N;

  // workspace layout (bytes)           size    lifetime
  // xT    @ 0                          32 MB   through kq gemm
  // Wkc   @ 32M, Wqc @ 34M, Wtv @ 36M   6 MB
  // W2Tc  @ 38M                         2 MB   dead after tmp gemm
  // W2p   @ 40M                        16 MB   dead after reduce
  // tmp   @ 56M                        32 MB   dead after kq gemm
  // vvT   @ 88M                        32 MB
  // P(kq) @ 120M                       32 MB   exp(kq/32), bf16
  // Spart @ 152M                        1 MB   16 slots x 16 x 1024 f32
  char* ws = (char*)d_ws;
  uint16_t* xT   = (uint16_t*)(ws);
  uint16_t* Wkc  = (uint16_t*)(ws + (32ull << 20));
  uint16_t* Wqc  = (uint16_t*)(ws + (34ull << 20));
  uint16_t* Wtv  = (uint16_t*)(ws + (36ull << 20));
  uint16_t* W2Tc = (uint16_t*)(ws + (38ull << 20));
  float*    W2p  = (float*)   (ws + (40ull << 20));
  uint16_t* tmp  = (uint16_t*)(ws + (56ull << 20));
  uint16_t* vvT  = (uint16_t*)(ws + (88ull << 20));
  uint16_t* P    = (uint16_t*)(ws + (120ull << 20));
  float*    Spart= (float*)   (ws + (152ull << 20));

  const dim3 tb(32, 8);
  // weights: cast Wk, Wq; transpose-cast Wv
  prep_w<<<dim3(N / 32, N / 32, 3), tb, 0, stream>>>(wk, wq, wv, Wkc, Wqc, Wtv);
  // W2T[j,i] = sum_n Wq[j,n] Wk[i,n]  (split-K=4 partials, then reduce+cast)
  gemm128_splitk<<<256, 256, 0, stream>>>(Wqc, Wkc, W2p);
  reduce_w2t<<<1024, 256, 0, stream>>>(W2p, W2Tc);
  // xT[b][d][n] = x[b][n][d]
  transpose_cast<<<dim3(D / 32, N / 32, BB), tb, 0, stream>>>(x, xT, N, D, DN, DN);
  // tmp[b][d][j] = sum_i xT[b][d][i] * W2T[j][i]
  gemm_bt256<0><<<256, 512, 0, stream>>>(xT, W2Tc, tmp, DN, 0, DN, 1.0f, Spart);
  // vvT[b][n][d] = sum_n' Wtv[n][n'] * xT[b][d][n']
  gemm_bt256<0><<<256, 512, 0, stream>>>(Wtv, xT, vvT, 0, DN, DN, 1.0f, Spart);
  // P[b][d][e] = exp( (1/32) sum_j tmp[b][d][j] * xT[b][e][j] ),  + Spart
  gemm_bt256<2><<<256, 512, 0, stream>>>(tmp, xT, P, DN, DN, DN, 0.03125f, Spart);
  // out[b][n][d] = ( sum_e vvT[b][n][e] * P[b][d][e] ) / S[b][d]
  gemm_bt256<3><<<256, 512, 0, stream>>>(vvT, P, out, DN, DN, DN, 1.0f, Spart);
}

// Round 4
// 282.491 us; speedup vs baseline: 1.1799x; 1.0327x over previous
//
#include <hip/hip_runtime.h>
#include <stdint.h>

// ---------------------------------------------------------------------------
// SelfAttention: out[b,n,d] = ( softmax( (X^T Wk)(X^T Wq)^T / 32 ) (X^T Wv) )^T
// B=16, N=D=1024.
//
// R5 algebra: kq = xT (Wk Wq^T) x -> 4 big GEMMs (tmp, vvT, kq(P), out).
// R6a fusion: softmax folded into GEMM epilogues (EPI=2 exp+Spart, EPI=3 /S).
// R7 (this): gemm structure changed from 256x256/1-block-per-CU/8-phase to
//   256x128 / 2-blocks-per-CU / single-buffer full-drain (R3's proven body):
//   - 512 blocks x 512 thr (8 waves, 4Mx2N, wave-tile 64x64, acc[4][4]).
//   - LDS 48 KiB single buffer (A 256x64 + B 128x64 bf16) -> 2 blocks/CU
//     resident (16 waves/CU): cross-BLOCK overlap hides the per-K-tile
//     vmcnt(0) drain + barriers (m97/m114 mechanism), replacing the
//     intra-block pipeline that 4 schedule variants failed to make pay.
//   - Same XOR-chunk LDS swizzle (slot cp holds k-chunk cp^(row&7));
//     ds_read_b128 conflict-free (counter-verified 0 in R3..R6).
// ---------------------------------------------------------------------------

typedef __bf16 bf16x8_t __attribute__((ext_vector_type(8)));
typedef float  f32x4_t  __attribute__((ext_vector_type(4)));

typedef __attribute__((address_space(3))) uint32_t as3_u32;
typedef __attribute__((address_space(1))) uint32_t as1_u32;

__device__ __forceinline__ void async_copy16(const void* g, const void* l) {
  __builtin_amdgcn_global_load_lds((const as1_u32*)(uintptr_t)g,
                                   (as3_u32*)(uint32_t)(uintptr_t)l,
                                   16, 0, 0);
}

__device__ __forceinline__ uint16_t f2bf(float f) {  // RNE
  uint32_t x = __float_as_uint(f);
  return (uint16_t)((x + 0x7fffu + ((x >> 16) & 1u)) >> 16);
}
__device__ __forceinline__ float bf2f(uint16_t b) {
  return __uint_as_float(((uint32_t)b) << 16);
}

// C[m,n] = alpha * sum_k A[m,k] * B[n,k].  M=N=K=1024 fixed per batch slice.
// Tile 256(M) x 128(N), BK=64.  512 blocks x 512 threads.
// EPI: 0 = bf16 C*alpha;  2 = bf16 exp(C*alpha) + Spart row partials;
//      3 = f32 C*alpha/S[col] (S = sum of 16 Spart slots).
template <int EPI>
__global__ __launch_bounds__(512, 4)
void gemm_bt256x128(const uint16_t* __restrict__ A,
                    const uint16_t* __restrict__ B,
                    void* __restrict__ Cv, size_t sA, size_t sB, size_t sC,
                    float alpha, float* __restrict__ Sp)
{
  __shared__ __align__(16) char smem[49152];
  char* As = smem;            // 256 x 64 bf16 = 32768 B
  char* Bs = smem + 32768;    // 128 x 64 bf16 = 16384 B

  // ---- XCD swizzle: lid%8 = XCD; 2 batches per XCD, 4x8 tiles per batch ----
  const int lid  = blockIdx.x;
  const int xcd  = lid & 7;
  const int slot = lid >> 3;            // 0..63
  const int z    = (xcd << 1) | (slot >> 5);
  const int t32  = slot & 31;
  const int bm0  = (t32 >> 3) << 8;     // 0,256,512,768
  const int bn0  = (t32 & 7) << 7;      // 0..896 step 128

  A += (size_t)z * sA + ((size_t)bm0 << 10);
  B += (size_t)z * sB + ((size_t)bn0 << 10);

  const int t    = threadIdx.x;
  const int lane = t & 63;
  const int w    = t >> 6;              // 0..7
  const int q    = lane >> 4;
  const int r16  = lane & 15;
  const int wm   = (w >> 1) << 6;       // 0,64,128,192
  const int wn   = (w & 1) << 6;        // 0,64

  // ---- staging constants: row pitch 128 B, slot cp holds chunk cp^(row&7) --
  const int g0  = t >> 3;               // 0..63
  const int cp  = t & 7;
  const int ce  = (cp ^ (g0 & 7)) << 3; // (g0+64s)&7 == g0&7, so ce is const
  const int so  = (g0 << 7) + (cp << 4);
  const uint16_t* Ag = A + ((size_t)g0 << 10) + ce;
  const uint16_t* Bg = B + ((size_t)g0 << 10) + ce;

  f32x4_t acc[4][4];
#pragma unroll
  for (int i = 0; i < 4; i++)
#pragma unroll
    for (int j = 0; j < 4; j++) acc[i][j] = (f32x4_t){0.f, 0.f, 0.f, 0.f};

  for (int k0 = 0; k0 < 1024; k0 += 64) {
    // A: 4 x 16B per thread (rows g0+64s); B: 2 x 16B (rows g0+64s).
#pragma unroll
    for (int s = 0; s < 4; ++s)
      async_copy16(Ag + (((size_t)s << 6) << 10) + k0, As + so + (s << 13));
#pragma unroll
    for (int s = 0; s < 2; ++s)
      async_copy16(Bg + (((size_t)s << 6) << 10) + k0, Bs + so + (s << 13));
    __syncthreads();   // full drain (vmcnt 0); hidden by co-resident block

#pragma unroll
    for (int kk = 0; kk < 2; ++kk) {
      bf16x8_t af[4], bfr[4];
#pragma unroll
      for (int mi = 0; mi < 4; ++mi) {
        const int m = wm + (mi << 4) + r16;
        const int c = (kk << 2) + q;
        af[mi] = *(const bf16x8_t*)(As + (m << 7) + ((c ^ (m & 7)) << 4));
      }
#pragma unroll
      for (int ni = 0; ni < 4; ++ni) {
        const int n = wn + (ni << 4) + r16;
        const int c = (kk << 2) + q;
        bfr[ni] = *(const bf16x8_t*)(Bs + (n << 7) + ((c ^ (n & 7)) << 4));
      }
      __builtin_amdgcn_s_setprio(1);
#pragma unroll
      for (int mi = 0; mi < 4; ++mi)
#pragma unroll
        for (int ni = 0; ni < 4; ++ni)
          acc[mi][ni] = __builtin_amdgcn_mfma_f32_16x16x32_bf16(
              af[mi], bfr[ni], acc[mi][ni], 0, 0, 0);
      __builtin_amdgcn_s_setprio(0);
    }
    __syncthreads();
  }

  // ---- epilogue.  C/D layout: col=lane&15, row=q*4+r (verified m89/m91) ----
  if constexpr (EPI == 3) {
    // f32 out, scaled by 1/S[col]; S = sum of 16 Spart slots per column.
    float inv[4];
#pragma unroll
    for (int ni = 0; ni < 4; ++ni) {
      const int c = bn0 + wn + (ni << 4) + r16;
      float S = 0.f;
#pragma unroll
      for (int p = 0; p < 16; ++p)
        S += Sp[((size_t)p << 14) + ((size_t)z << 10) + c];
      inv[ni] = 1.0f / S;
    }
    float* C = (float*)Cv + (size_t)z * sC;
#pragma unroll
    for (int mi = 0; mi < 4; ++mi)
#pragma unroll
      for (int ni = 0; ni < 4; ++ni)
#pragma unroll
        for (int r = 0; r < 4; ++r) {
          const int row = bm0 + wm + (mi << 4) + (q << 2) + r;
          const int col = bn0 + wn + (ni << 4) + r16;
          C[((size_t)row << 10) + col] = acc[mi][ni][r] * alpha * inv[ni];
        }
  } else {
    // bf16 out via per-wave-private LDS staging -> full 128-B row stores.
    // EPI==2 additionally applies exp() and emits per-row partial sums.
    float* reg = (float*)smem + (size_t)w * 1056;   // 16 x 66 floats
    uint16_t* C = (uint16_t*)Cv + (size_t)z * sC;
    float* SpW = Sp + ((size_t)(((bn0 >> 7) << 1) + (w & 1)) << 14)
                    + ((size_t)z << 10);
#pragma unroll
    for (int mi = 0; mi < 4; ++mi) {
      if constexpr (EPI == 2) {
        float ev[4][4];
#pragma unroll
        for (int ni = 0; ni < 4; ++ni)
#pragma unroll
          for (int r = 0; r < 4; ++r) {
            ev[ni][r] = __expf(acc[mi][ni][r] * alpha);
            reg[((q << 2) + r) * 66 + (ni << 4) + r16] = ev[ni][r];
          }
#pragma unroll
        for (int r = 0; r < 4; ++r) {
          float s = ev[0][r] + ev[1][r] + ev[2][r] + ev[3][r];
          s += __shfl_xor(s, 1, 16);
          s += __shfl_xor(s, 2, 16);
          s += __shfl_xor(s, 4, 16);
          s += __shfl_xor(s, 8, 16);
          if (r16 == 0)
            SpW[bm0 + wm + (mi << 4) + (q << 2) + r] = s;
        }
      } else {
#pragma unroll
        for (int ni = 0; ni < 4; ++ni)
#pragma unroll
          for (int r = 0; r < 4; ++r)
            reg[((q << 2) + r) * 66 + (ni << 4) + r16] = acc[mi][ni][r] * alpha;
      }
#pragma unroll
      for (int it = 0; it < 8; ++it) {
        const int rr = (it << 1) + (lane >> 5);     // 0..15
        const int cc = (lane & 31) << 1;            // 0..62
        const float2 v = *(const float2*)(reg + rr * 66 + cc);
        const uint32_t p = (uint32_t)f2bf(v.x) | ((uint32_t)f2bf(v.y) << 16);
        const int row = bm0 + wm + (mi << 4) + rr;
        const int col = bn0 + wn + cc;
        *(uint32_t*)(C + ((size_t)row << 10) + col) = p;
      }
    }
  }
}

// Split-K GEMM for W2T = Wq Wk^T: P[slice][m,n] = sum_{k in slice} A[m,k]B[n,k]
// M=N=1024, K=1024, splitK=4 (256 k each).  grid 256 x 256thr.
__global__ __launch_bounds__(256, 4)
void gemm128_splitk(const uint16_t* __restrict__ A, const uint16_t* __restrict__ B,
                    float* __restrict__ P)
{
  __shared__ __align__(16) char smem[32768];
  char* As = smem;
  char* Bs = smem + 16384;

  const int slice = blockIdx.x >> 6;
  const int tile  = blockIdx.x & 63;
  const int bm0   = (tile >> 3) << 7;
  const int bn0   = (tile & 7) << 7;
  const int koff  = slice << 8;

  const int t    = threadIdx.x;
  const int lane = t & 63;
  const int w    = t >> 6;
  const int q    = lane >> 4;
  const int r16  = lane & 15;
  const int wm   = (w >> 1) << 6;
  const int wn   = (w & 1) << 6;

  f32x4_t acc[4][4];
#pragma unroll
  for (int i = 0; i < 4; i++)
#pragma unroll
    for (int j = 0; j < 4; j++) acc[i][j] = (f32x4_t){0.f, 0.f, 0.f, 0.f};

  for (int k0 = koff; k0 < koff + 256; k0 += 64) {
#pragma unroll
    for (int i = 0; i < 4; i++) {
      const int o  = (i << 12) + (t << 4);
      const int m  = o >> 7;
      const int cp = (o >> 4) & 7;
      const int c  = cp ^ (m & 7);
      async_copy16(A + (size_t)(bm0 + m) * 1024 + (size_t)(k0 + (c << 3)), As + o);
      async_copy16(B + (size_t)(bn0 + m) * 1024 + (size_t)(k0 + (c << 3)), Bs + o);
    }
    __syncthreads();
#pragma unroll
    for (int kk = 0; kk < 2; kk++) {
      bf16x8_t af[4], bfr[4];
#pragma unroll
      for (int mi = 0; mi < 4; mi++) {
        const int m = wm + (mi << 4) + r16;
        const int c = (kk << 2) + q;
        af[mi] = *(const bf16x8_t*)(As + (m << 7) + ((c ^ (m & 7)) << 4));
      }
#pragma unroll
      for (int ni = 0; ni < 4; ni++) {
        const int n = wn + (ni << 4) + r16;
        const int c = (kk << 2) + q;
        bfr[ni] = *(const bf16x8_t*)(Bs + (n << 7) + ((c ^ (n & 7)) << 4));
      }
#pragma unroll
      for (int mi = 0; mi < 4; mi++)
#pragma unroll
        for (int ni = 0; ni < 4; ni++)
          acc[mi][ni] = __builtin_amdgcn_mfma_f32_16x16x32_bf16(
              af[mi], bfr[ni], acc[mi][ni], 0, 0, 0);
    }
    __syncthreads();
  }

  float* C = P + (size_t)slice * (1024u * 1024u);
#pragma unroll
  for (int mi = 0; mi < 4; mi++)
#pragma unroll
    for (int ni = 0; ni < 4; ni++)
#pragma unroll
      for (int r = 0; r < 4; r++) {
        const int row = bm0 + wm + (mi << 4) + (q << 2) + r;
        const int col = bn0 + wn + (ni << 4) + r16;
        C[((size_t)row << 10) + col] = acc[mi][ni][r];
      }
}

// W2Tc = bf16( P[0] + P[1] + P[2] + P[3] ).  grid 1024 x 256thr, 4 elems/thr.
__global__ __launch_bounds__(256)
void reduce_w2t(const float* __restrict__ P, uint16_t* __restrict__ W)
{
  const size_t i4 = (((size_t)blockIdx.x << 8) + threadIdx.x) << 2;
  const float4 a = *(const float4*)(P + i4);
  const float4 b = *(const float4*)(P + (1u << 20) + i4);
  const float4 c = *(const float4*)(P + (2u << 20) + i4);
  const float4 d = *(const float4*)(P + (3u << 20) + i4);
  ushort4 r;
  r.x = f2bf(a.x + b.x + c.x + d.x);
  r.y = f2bf(a.y + b.y + c.y + d.y);
  r.z = f2bf(a.z + b.z + c.z + d.z);
  r.w = f2bf(a.w + b.w + c.w + d.w);
  *(ushort4*)(W + i4) = r;
}

// z=0: cast Wk->o0 (row-major); z=1: cast Wq->o1; z=2: transpose-cast Wv->o2.
__global__ __launch_bounds__(256)
void prep_w(const float* __restrict__ w0, const float* __restrict__ w1,
            const float* __restrict__ w2, uint16_t* __restrict__ o0,
            uint16_t* __restrict__ o1, uint16_t* __restrict__ o2)
{
  __shared__ float tile[32][33];
  const int z = blockIdx.z;
  const int c0 = blockIdx.x << 5;
  const int r0 = blockIdx.y << 5;
  const int tx = threadIdx.x;
  const int ty = threadIdx.y;
  if (z < 2) {
    const float* src = z ? w1 : w0;
    uint16_t* dst = z ? o1 : o0;
#pragma unroll
    for (int i = 0; i < 32; i += 8)
      dst[(size_t)(r0 + ty + i) * 1024 + (c0 + tx)] =
          f2bf(src[(size_t)(r0 + ty + i) * 1024 + (c0 + tx)]);
  } else {
#pragma unroll
    for (int i = 0; i < 32; i += 8)
      tile[ty + i][tx] = w2[(size_t)(r0 + ty + i) * 1024 + (c0 + tx)];
    __syncthreads();
#pragma unroll
    for (int i = 0; i < 32; i += 8)
      o2[(size_t)(c0 + ty + i) * 1024 + (r0 + tx)] = f2bf(tile[tx][ty + i]);
  }
}

// dst[c][r] = (bf16) src[r][c]; src: R x C fp32 row-major.  32x32 LDS tiles.
__global__ __launch_bounds__(256)
void transpose_cast(const float* __restrict__ src, uint16_t* __restrict__ dst,
                    int R, int Ccols, size_t sStride, size_t dStride)
{
  __shared__ float tile[32][33];
  const int z = blockIdx.z;
  src += (size_t)z * sStride;
  dst += (size_t)z * dStride;
  const int c0 = blockIdx.x << 5;
  const int r0 = blockIdx.y << 5;
  const int tx = threadIdx.x;
  const int ty = threadIdx.y;
#pragma unroll
  for (int i = 0; i < 32; i += 8)
    tile[ty + i][tx] = src[(size_t)(r0 + ty + i) * Ccols + (c0 + tx)];
  __syncthreads();
#pragma unroll
  for (int i = 0; i < 32; i += 8)
    dst[(size_t)(c0 + ty + i) * R + (r0 + tx)] = f2bf(tile[tx][ty + i]);
}

extern "C" void kernel_launch(void* const* d_in, const int* in_sizes, int n_in,
                              void* d_out, int out_size, void* d_ws, size_t ws_size,
                              hipStream_t stream)
{
  const float* x  = (const float*)d_in[0];
  const float* wk = (const float*)d_in[1];
  const float* wq = (const float*)d_in[2];
  const float* wv = (const float*)d_in[3];
  float* out = (float*)d_out;

  constexpr int BB = 16, N = 1024, D = 1024;
  constexpr size_t DN = (size_t)D * N;

  // workspace layout (bytes)           size    lifetime
  // xT    @ 0                          32 MB   through kq gemm
  // Wkc   @ 32M, Wqc @ 34M, Wtv @ 36M   6 MB
  // W2Tc  @ 38M                         2 MB   dead after tmp gemm
  // W2p   @ 40M                        16 MB   dead after reduce
  // tmp   @ 56M                        32 MB   dead after kq gemm
  // vvT   @ 88M                        32 MB
  // P(kq) @ 120M                       32 MB   exp(kq/32), bf16
  // Spart @ 152M                        1 MB   16 slots x 16 x 1024 f32
  char* ws = (char*)d_ws;
  uint16_t* xT   = (uint16_t*)(ws);
  uint16_t* Wkc  = (uint16_t*)(ws + (32ull << 20));
  uint16_t* Wqc  = (uint16_t*)(ws + (34ull << 20));
  uint16_t* Wtv  = (uint16_t*)(ws + (36ull << 20));
  uint16_t* W2Tc = (uint16_t*)(ws + (38ull << 20));
  float*    W2p  = (float*)   (ws + (40ull << 20));
  uint16_t* tmp  = (uint16_t*)(ws + (56ull << 20));
  uint16_t* vvT  = (uint16_t*)(ws + (88ull << 20));
  uint16_t* P    = (uint16_t*)(ws + (120ull << 20));
  float*    Spart= (float*)   (ws + (152ull << 20));

  const dim3 tb(32, 8);
  // weights: cast Wk, Wq; transpose-cast Wv
  prep_w<<<dim3(N / 32, N / 32, 3), tb, 0, stream>>>(wk, wq, wv, Wkc, Wqc, Wtv);
  // W2T[j,i] = sum_n Wq[j,n] Wk[i,n]  (split-K=4 partials, then reduce+cast)
  gemm128_splitk<<<256, 256, 0, stream>>>(Wqc, Wkc, W2p);
  reduce_w2t<<<1024, 256, 0, stream>>>(W2p, W2Tc);
  // xT[b][d][n] = x[b][n][d]
  transpose_cast<<<dim3(D / 32, N / 32, BB), tb, 0, stream>>>(x, xT, N, D, DN, DN);
  // tmp[b][d][j] = sum_i xT[b][d][i] * W2T[j][i]
  gemm_bt256x128<0><<<512, 512, 0, stream>>>(xT, W2Tc, tmp, DN, 0, DN, 1.0f, Spart);
  // vvT[b][n][d] = sum_n' Wtv[n][n'] * xT[b][d][n']
  gemm_bt256x128<0><<<512, 512, 0, stream>>>(Wtv, xT, vvT, 0, DN, DN, 1.0f, Spart);
  // P[b][d][e] = exp( (1/32) sum_j tmp[b][d][j] * xT[b][e][j] ),  + Spart
  gemm_bt256x128<2><<<512, 512, 0, stream>>>(tmp, xT, P, DN, DN, DN, 0.03125f, Spart);
  // out[b][n][d] = ( sum_e vvT[b][n][e] * P[b][d][e] ) / S[b][d]
  gemm_bt256x128<3><<<512, 512, 0, stream>>>(vvT, P, out, DN, DN, DN, 1.0f, Spart);
}